// Round 2
// baseline (260.636 us; speedup 1.0000x reference)
//
#include <hip/hip_runtime.h>

#define BATCH 8192
#define FEATS 4096
#define CHUNKS 128                        // row chunks for partial sums
#define ROWS_PER_CHUNK (BATCH / CHUNKS)   // 64
#define SROWS 16                          // rows per block in scale pass
#define NRBLK (FEATS / 256)               // 16 reduce_mean blocks

typedef float v4f __attribute__((ext_vector_type(4)));  // native vector for nontemporal builtin

// ws layout: [0, CHUNKS*FEATS) doubles = partial column sums (4 MB)
//            then FEATS doubles = means (32 KB)
//            then NRBLK doubles = per-block min
//            then NRBLK doubles = per-block max
//            then FEATS floats  = per-feature scale (16 KB)

__global__ __launch_bounds__(256) void colsum_part(const float* __restrict__ in,
                                                   double* __restrict__ partials) {
    // grid.x = 4 column groups of 1024 cols; grid.y = CHUNKS row chunks
    const int colBase = blockIdx.x * 1024 + threadIdx.x * 4;
    const int row0 = blockIdx.y * ROWS_PER_CHUNK;
    const float4* p = (const float4*)in + (size_t)row0 * (FEATS / 4) + (colBase >> 2);
    double a0 = 0.0, a1 = 0.0, a2 = 0.0, a3 = 0.0;
#pragma unroll 16
    for (int r = 0; r < ROWS_PER_CHUNK; ++r) {
        float4 v = p[(size_t)r * (FEATS / 4)];
        a0 += (double)v.x; a1 += (double)v.y; a2 += (double)v.z; a3 += (double)v.w;
    }
    double* dst = partials + (size_t)blockIdx.y * FEATS + colBase;
    dst[0] = a0; dst[1] = a1; dst[2] = a2; dst[3] = a3;
}

__global__ __launch_bounds__(256) void reduce_mean(const double* __restrict__ partials,
                                                   double* __restrict__ means,
                                                   double* __restrict__ bmin,
                                                   double* __restrict__ bmax) {
    const int c = blockIdx.x * 256 + threadIdx.x;
    double s = 0.0;
#pragma unroll 8
    for (int k = 0; k < CHUNKS; ++k) s += partials[(size_t)k * FEATS + c];
    const double m = s * (1.0 / (double)BATCH);  // /8192 exact pow2 scale
    means[c] = m;

    // block min/max: wave shuffle reduce, then 4 wave leaders via shared
    double lmin = m, lmax = m;
#pragma unroll
    for (int off = 32; off > 0; off >>= 1) {
        lmin = fmin(lmin, __shfl_down(lmin, off));
        lmax = fmax(lmax, __shfl_down(lmax, off));
    }
    __shared__ double smin[4], smax[4];
    const int wv = threadIdx.x >> 6;
    if ((threadIdx.x & 63) == 0) { smin[wv] = lmin; smax[wv] = lmax; }
    __syncthreads();
    if (threadIdx.x == 0) {
        bmin[blockIdx.x] = fmin(fmin(smin[0], smin[1]), fmin(smin[2], smin[3]));
        bmax[blockIdx.x] = fmax(fmax(smax[0], smax[1]), fmax(smax[2], smax[3]));
    }
}

__global__ __launch_bounds__(1024) void config_kernel(const double* __restrict__ means,
                                                      const double* __restrict__ bmin,
                                                      const double* __restrict__ bmax,
                                                      const float* __restrict__ noise,
                                                      float* __restrict__ scale) {
    __shared__ unsigned s_hist[FEATS + 1];
    __shared__ double s_mm[2];
    const int tid = threadIdx.x;

    if (tid == 0) {
        double a = bmin[0], b = bmax[0];
        for (int i = 1; i < NRBLK; ++i) { a = fmin(a, bmin[i]); b = fmax(b, bmax[i]); }
        s_mm[0] = a; s_mm[1] = b;
    }
    for (int i = tid; i < FEATS + 1; i += 1024) s_hist[i] = 0;
    __syncthreads();

    const double xmin = s_mm[0];
    const double denom = s_mm[1] - xmin;

    int binr[4];
#pragma unroll
    for (int k = 0; k < 4; ++k) {
        int c = tid + k * 1024;
        // match numpy op order: F*(x - xmin) then divide, truncate toward zero
        double b = ((double)FEATS * (means[c] - xmin)) / denom;
        int bi = (int)b;
        binr[k] = bi;
        atomicAdd(&s_hist[bi], 1u);
    }
    __syncthreads();

    const double K = -2.302585092994045684017991454684364208;  // ln(0.1)
#pragma unroll
    for (int k = 0; k < 4; ++k) {
        int c = tid + k * 1024;
        unsigned cnt = s_hist[binr[k]];
        double dr = (cnt == 1u) ? 0.1 : exp(K / (0.6 * (double)cnt));
        double sg = sqrt(dr / (1.0 - dr));
        scale[c] = (float)(1.0 + sg * (double)noise[c]);
    }
}

__global__ __launch_bounds__(256) void scale_kernel(const float4* __restrict__ in,
                                                    const float4* __restrict__ scale,
                                                    float4* __restrict__ out) {
    // blockIdx.x & 3 -> column group (256 float4 cols), blockIdx.x >> 2 -> row group
    const int col = (blockIdx.x & 3) * 256 + threadIdx.x;  // float4-column, 0..1023
    const int row0 = (blockIdx.x >> 2) * SROWS;
    const float4 s = scale[col];  // loaded ONCE per thread, reused for SROWS rows
    const float4* pin = in + (size_t)row0 * (FEATS / 4) + col;
    float4* pout = out + (size_t)row0 * (FEATS / 4) + col;
#pragma unroll
    for (int r = 0; r < SROWS; ++r) {
        float4 v = pin[(size_t)r * (FEATS / 4)];
        v.x *= s.x; v.y *= s.y; v.z *= s.z; v.w *= s.w;
        // nontemporal: don't let the out-stream evict the L3-resident input
        v4f nv = {v.x, v.y, v.z, v.w};
        __builtin_nontemporal_store(nv, (v4f*)&pout[(size_t)r * (FEATS / 4)]);
    }
}

extern "C" void kernel_launch(void* const* d_in, const int* in_sizes, int n_in,
                              void* d_out, int out_size, void* d_ws, size_t ws_size,
                              hipStream_t stream) {
    const float* in = (const float*)d_in[0];
    const float* noise = (const float*)d_in[1];
    float* out = (float*)d_out;
    double* partials = (double*)d_ws;
    double* means = partials + (size_t)CHUNKS * FEATS;
    double* bmin = means + FEATS;
    double* bmax = bmin + NRBLK;
    float* scale = (float*)(bmax + NRBLK);

    dim3 g1(4, CHUNKS);
    colsum_part<<<g1, 256, 0, stream>>>(in, partials);
    reduce_mean<<<NRBLK, 256, 0, stream>>>(partials, means, bmin, bmax);
    config_kernel<<<1, 1024, 0, stream>>>(means, bmin, bmax, noise, scale);
    scale_kernel<<<4 * (BATCH / SROWS), 256, 0, stream>>>(
        (const float4*)in, (const float4*)scale, (float4*)out);
}